// Round 4
// baseline (409.434 us; speedup 1.0000x reference)
//
#include <hip/hip_runtime.h>

// Problem constants (from reference)
#define TT 2048
#define BB 4096
#define OUT_STRIDE_T (BB * 4)                  // floats per timestep slab [B,4]
#define OUT_LSTM ((size_t)TT * (size_t)BB * 4) // floats per LSTM output tensor

typedef _Float16 half2_t __attribute__((ext_vector_type(2)));

static __device__ __forceinline__ float fast_exp2(float a) { return __builtin_amdgcn_exp2f(a); }
static __device__ __forceinline__ float fast_rcp(float a)  { return __builtin_amdgcn_rcpf(a); }

// f32 pair -> packed f16 (RTZ pack instruction; bit-cast to our vector type).
static __device__ __forceinline__ half2_t pkrtz(float a, float b) {
    return __builtin_bit_cast(half2_t, __builtin_amdgcn_cvt_pkrtz(a, b));
}

// DPP cross-lane moves (pure VALU). quad_perm xor1=0xB1, xor2=0x4E; row_shr:4=0x114.
template<int CTRL>
static __device__ __forceinline__ float dpp_f32(float x) {
    int r = __builtin_amdgcn_update_dpp(0, __builtin_bit_cast(int, x), CTRL, 0xF, 0xF, false);
    return __builtin_bit_cast(float, r);
}
template<int CTRL>
static __device__ __forceinline__ half2_t dpp_h2(half2_t x) {
    int r = __builtin_amdgcn_update_dpp(0, __builtin_bit_cast(int, x), CTRL, 0xF, 0xF, false);
    return __builtin_bit_cast(half2_t, r);
}
// Fused shift+select: banks 1,3 (layer-2 lanes) receive src shifted right by 4
// lanes (layer-1's value); banks 0,2 (layer-1 lanes) keep `old` (= packed x).
template<int CTRL>
static __device__ __forceinline__ half2_t dpp_h2_sel(half2_t src, half2_t old) {
    int r = __builtin_amdgcn_update_dpp(__builtin_bit_cast(int, old),
                                        __builtin_bit_cast(int, src),
                                        CTRL, 0xF, 0xA, false);
    return __builtin_bit_cast(half2_t, r);
}

static __device__ __forceinline__ float fdot2(half2_t a, half2_t b, float c) {
    return __builtin_amdgcn_fdot2(a, b, c, false);
}

// Lane layout: 16 lanes per batch element b (one 16-lane DPP row per b).
//   role = lane & 15:  j = role&3 (hidden unit), isL2 = (role>>2)&1 (layer),
//   lstm = role>>3. Layer 2 runs one timestep skewed behind layer 1.
__global__ __launch_bounds__(256, 1) void lstm2x2_kernel(
    const float* __restrict__ x,
    const float* __restrict__ wihd, const float* __restrict__ whhd,
    const float* __restrict__ bihd, const float* __restrict__ bhhd,
    const float* __restrict__ wihn, const float* __restrict__ whhn,
    const float* __restrict__ bihn, const float* __restrict__ bhhn,
    float* __restrict__ out)
{
    const int gtid = blockIdx.x * blockDim.x + threadIdx.x;
    const int b    = gtid >> 4;
    const int role = gtid & 15;
    const int j    = role & 3;
    const int isL2 = (role >> 2) & 1;
    const int lstm = (role >> 3) & 1;

    const float* wih = lstm ? wihn : wihd;
    const float* whh = lstm ? whhn : whhd;
    const float* bih = lstm ? bihn : bihd;
    const float* bhh = lstm ? bhhn : bhhd;

    constexpr float L2E = 1.44269504088896340736f;
    constexpr float NEG2L2E = -2.0f * L2E;

    // Per-lane weights packed to f16 pairs (RNE via scalar casts), prescaled:
    //   i,f,o rows: * -log2(e)  -> p = exp2(z') = e^{-z}
    //   g row:      * -2log2(e) -> p = e^{-2z}
    // Column pairing (m0,m1),(m2,m3); W_hh cols (and W_ih cols for layer 2)
    // XOR-j permuted to match the quad_perm gather order.
    half2_t WA01[4], WA23[4], WB01[4], WB23[4];
    float BS[4];
#pragma unroll
    for (int g = 0; g < 4; ++g) {
        const float sc = (g == 2) ? NEG2L2E : -L2E;
        const int row = isL2 * 16 + g * 4 + j;   // torch gate order i,f,g,o
        float wa[4], wb[4];
#pragma unroll
        for (int m = 0; m < 4; ++m) {
            const int colA = isL2 ? (j ^ m) : m; // layer1 input = x (natural)
            wa[m] = wih[row * 4 + colA] * sc;
            wb[m] = whh[row * 4 + (j ^ m)] * sc;
        }
        WA01[g] = half2_t{(_Float16)wa[0], (_Float16)wa[1]};
        WA23[g] = half2_t{(_Float16)wa[2], (_Float16)wa[3]};
        WB01[g] = half2_t{(_Float16)wb[0], (_Float16)wb[1]};
        WB23[g] = half2_t{(_Float16)wb[2], (_Float16)wb[3]};
        BS[g]   = (bih[row] + bhh[row]) * sc;
    }

    // x prefetch ring, depth 8 (f32; converted to f16 pairs at use so the
    // cvt never waits on the fresh load).
    const float4* xb = reinterpret_cast<const float4*>(x) + b;
    float4 xr[8];
#pragma unroll
    for (int i = 0; i < 8; ++i) xr[i] = xb[(size_t)i * BB];

    float* outp = out + (size_t)lstm * OUT_LSTM + (size_t)b * 4 + j;

    float h = 0.0f, c = 0.0f;

    // One LSTM step. Consumes previous h (member state), updates c, returns hn.
    auto do_step = [&](float4 xv) -> float {
        half2_t xp01 = pkrtz(xv.x, xv.y);
        half2_t xp23 = pkrtz(xv.z, xv.w);

        // Own-layer h pairs (f16): {h_j, h_{j^1}}, {h_{j^2}, h_{j^3}}.
        const float o1 = dpp_f32<0xB1>(h);
        half2_t hp01 = pkrtz(h, o1);
        half2_t hp23 = dpp_h2<0x4E>(hp01);
        // A operand: layer-1 lanes keep x pairs; layer-2 lanes take layer-1's
        // h pairs (row_shr:4 within the 16-lane row) — one DPP each.
        half2_t a01 = dpp_h2_sel<0x114>(hp01, xp01);
        half2_t a23 = dpp_h2_sel<0x114>(hp23, xp23);

        // Gate pre-activations: 4 chained dot2 per gate, 4-gate ILP.
        float z0 = fdot2(WA01[0], a01, BS[0]);
        z0 = fdot2(WA23[0], a23, z0);
        z0 = fdot2(WB01[0], hp01, z0);
        z0 = fdot2(WB23[0], hp23, z0);

        float z1 = fdot2(WA01[1], a01, BS[1]);
        z1 = fdot2(WA23[1], a23, z1);
        z1 = fdot2(WB01[1], hp01, z1);
        z1 = fdot2(WB23[1], hp23, z1);

        float z2 = fdot2(WA01[2], a01, BS[2]);
        z2 = fdot2(WA23[2], a23, z2);
        z2 = fdot2(WB01[2], hp01, z2);
        z2 = fdot2(WB23[2], hp23, z2);

        float z3 = fdot2(WA01[3], a01, BS[3]);
        z3 = fdot2(WA23[3], a23, z3);
        z3 = fdot2(WB01[3], hp01, z3);
        z3 = fdot2(WB23[3], hp23, z3);

        // p_i = e^{-z_i}, p_f = e^{-z_f}, p_g = e^{-2 z_g}, p_o = e^{-z_o}
        const float p0 = fast_exp2(z0);
        const float p1 = fast_exp2(z1);
        const float p2 = fast_exp2(z2);
        const float p3 = fast_exp2(z3);

        // c = sigma(zf)*c + sigma(zi)*tanh(zg), single rcp via common denom:
        //   c = [c*(1+p0)(1+p2) + (1+p1)(1-p2)] / [(1+p0)(1+p1)(1+p2)]
        const float e0 = 1.0f + p0;
        const float e1 = 1.0f + p1;
        const float e2 = 1.0f + p2;
        const float u2 = e0 * e2;
        const float D  = u2 * e1;
        const float t2 = e1 * (1.0f - p2);
        const float N  = fmaf(c, u2, t2);
        c = N * fast_rcp(D);

        // h = sigma(zo) * tanh(c), single rcp:
        //   q = e^{-2|c|};  h = sign(c) * (1-q) / ((1+p3)(1+q))
        const float q   = fast_exp2(NEG2L2E * fabsf(c));
        const float Dh  = (1.0f + p3) * (1.0f + q);
        const float mag = (1.0f - q) * fast_rcp(Dh);
        return copysignf(mag, c);
    };

    // Peel s=0 (t=0 on layer-1 lanes); zero layer-2 state (pipeline fill).
    {
        float hn = do_step(xr[0]);
        xr[0] = xb[(size_t)8 * BB];
        if (isL2) { hn = 0.0f; c = 0.0f; }
        h = hn;
    }

    // Main loop: iteration s computes t=s (layer 1) / t=s-1 (layer 2).
    // 2048 iters as 256 x 8: ring index static per body, stores batched 8-wide.
    float hs[8];
    for (int u = 0; u < 256; ++u) {
#pragma unroll
        for (int kk = 0; kk < 8; ++kk) {
            const int s = 1 + u * 8 + kk;
            const int k = s & 7;            // == (kk+1)&7, compile-time
            float hn = do_step(xr[k]);
            int tld = s + 8; if (tld > TT - 1) tld = TT - 1;
            xr[k] = xb[(size_t)tld * BB];
            h = hn;
            hs[kk] = hn;
        }
        if (isL2) {
            float* op = outp + (size_t)(u * 8) * OUT_STRIDE_T;
#pragma unroll
            for (int kk = 0; kk < 8; ++kk)
                op[(size_t)kk * OUT_STRIDE_T] = hs[kk];
        }
    }
}

extern "C" void kernel_launch(void* const* d_in, const int* in_sizes, int n_in,
                              void* d_out, int out_size, void* d_ws, size_t ws_size,
                              hipStream_t stream)
{
    const float* x    = (const float*)d_in[0];
    const float* wihd = (const float*)d_in[1];
    const float* whhd = (const float*)d_in[2];
    const float* bihd = (const float*)d_in[3];
    const float* bhhd = (const float*)d_in[4];
    const float* wihn = (const float*)d_in[5];
    const float* whhn = (const float*)d_in[6];
    const float* bihn = (const float*)d_in[7];
    const float* bhhn = (const float*)d_in[8];
    float* out = (float*)d_out;

    // 4096 batch elems * 16 lanes = 65536 threads = 256 blocks of 256.
    lstm2x2_kernel<<<dim3(256), dim3(256), 0, stream>>>(
        x, wihd, whhd, bihd, bhhd, wihn, whhn, bihn, bhhn, out);
}

// Round 5
// 332.863 us; speedup vs baseline: 1.2300x; 1.2300x over previous
//
#include <hip/hip_runtime.h>

// Problem constants (from reference)
#define TT 2048
#define BB 4096
#define OUT_STRIDE_T (BB * 4)                  // floats per timestep slab [B,4]
#define OUT_LSTM ((size_t)TT * (size_t)BB * 4) // floats per LSTM output tensor

typedef float f2 __attribute__((ext_vector_type(2)));

static __device__ __forceinline__ float fast_exp2(float a) { return __builtin_amdgcn_exp2f(a); }
static __device__ __forceinline__ float fast_rcp(float a)  { return __builtin_amdgcn_rcpf(a); }

// DPP cross-lane move (pure VALU — no DS pipe, no lgkmcnt stall).
// quad_perm xor1=0xB1, xor2=0x4E, xor3=0x1B; row_shr:4 = 0x114.
template<int CTRL>
static __device__ __forceinline__ float dpp_f32(float x) {
    int xi = __builtin_bit_cast(int, x);
    int r  = __builtin_amdgcn_update_dpp(0, xi, CTRL, 0xF, 0xF, true);
    return __builtin_bit_cast(float, r);
}

// Packed dual-FP32 FMA (full rate on CDNA3+): d = a*b + c per 32-bit half.
static __device__ __forceinline__ f2 pk_fma(f2 a, f2 b, f2 c) {
    f2 d;
    asm("v_pk_fma_f32 %0, %1, %2, %3" : "=v"(d) : "v"(a), "v"(b), "v"(c));
    return d;
}

// Lane layout: 16 lanes per batch element b.
//   role = gtid & 15:  j = role&3 (hidden unit), isL2 = (role>>2)&1 (layer),
//   lstm = role>>3 (0 = dropout-weights LSTM, 1 = no-dropout LSTM).
// Layer 2 runs one timestep skewed behind layer 1 (pipelined via DPP row_shr:4),
// so every lane executes the identical instruction stream each iteration.
__global__ __launch_bounds__(256, 1) void lstm2x2_kernel(
    const float* __restrict__ x,
    const float* __restrict__ wihd, const float* __restrict__ whhd,
    const float* __restrict__ bihd, const float* __restrict__ bhhd,
    const float* __restrict__ wihn, const float* __restrict__ whhn,
    const float* __restrict__ bihn, const float* __restrict__ bhhn,
    float* __restrict__ out)
{
    const int gtid = blockIdx.x * blockDim.x + threadIdx.x;
    const int b    = gtid >> 4;
    const int role = gtid & 15;
    const int j    = role & 3;
    const int isL2 = (role >> 2) & 1;
    const int lstm = (role >> 3) & 1;

    const float* wih = lstm ? wihn : wihd;
    const float* whh = lstm ? whhn : whhd;
    const float* bih = lstm ? bihn : bihd;
    const float* bhh = lstm ? bhhn : bhhd;

    constexpr float L2E = 1.44269504088896340736f;
    constexpr float NEG2L2E = -2.0f * L2E;

    // Per-lane packed weights, prescaled so activations need only exp2+rcp:
    //   i,f,o rows: * -log2(e)   -> p = exp2(z') = e^{-z}
    //   g row:      * -2*log2(e) -> p = e^{-2z}
    // Pairing is over the input index m: pair {m=0,1} and {m=2,3}, so the
    // A-operand pairs come straight from the float4 x load / DPP results.
    // W_hh columns (and W_ih columns for layer 2) are XOR-j permuted to match
    // the quad_perm gather order with zero fixup ops.
    f2 WA01[4], WA23[4], WB01[4], WB23[4], BZ[4];
#pragma unroll
    for (int g = 0; g < 4; ++g) {
        const float sc = (g == 2) ? NEG2L2E : -L2E;
        const int row = isL2 * 16 + g * 4 + j;   // torch gate order i,f,g,o
        float wa[4], wb[4];
#pragma unroll
        for (int m = 0; m < 4; ++m) {
            const int colA = isL2 ? (j ^ m) : m; // layer1 input = x (natural)
            wa[m] = wih[row * 4 + colA] * sc;
            wb[m] = whh[row * 4 + (j ^ m)] * sc;
        }
        WA01[g] = f2{wa[0], wa[1]};
        WA23[g] = f2{wa[2], wa[3]};
        WB01[g] = f2{wb[0], wb[1]};
        WB23[g] = f2{wb[2], wb[3]};
        BZ[g]   = f2{(bih[row] + bhh[row]) * sc, 0.0f};
    }

    // x prefetch ring, depth 8 (~8 steps covers HBM latency). All lanes load
    // (L2 lanes duplicate L1's address -> coalesces, no extra HBM lines).
    const float4* xb = reinterpret_cast<const float4*>(x) + b;
    float4 xr[8];
#pragma unroll
    for (int i = 0; i < 8; ++i) xr[i] = xb[(size_t)i * BB];

    float* outp = out + (size_t)lstm * OUT_LSTM + (size_t)b * 4 + j;

    float h = 0.0f, c = 0.0f;

    // One LSTM step for this lane's cell. Uses/updates h (via return) and c.
    auto do_step = [&](float4 xk) -> float {
        // Cross-lane gathers on previous-step h — all DPP (VALU), parallel
        // off h (short chain front).
        const float o1 = dpp_f32<0xB1>(h);   // own-quad h[j^1]
        const float o2 = dpp_f32<0x4E>(h);   // own-quad h[j^2]
        const float o3 = dpp_f32<0x1B>(h);   // own-quad h[j^3]
        const float i0 = dpp_f32<0x114>(h);  // layer-1 h[j^0] (for L2 lanes)
        const float i1 = dpp_f32<0x114>(o1); // layer-1 h[j^1]
        const float i2 = dpp_f32<0x114>(o2); // layer-1 h[j^2]
        const float i3 = dpp_f32<0x114>(o3); // layer-1 h[j^3]

        f2 A01, A23, H01, H23;
        A01.x = isL2 ? i0 : xk.x;
        A01.y = isL2 ? i1 : xk.y;
        A23.x = isL2 ? i2 : xk.z;
        A23.y = isL2 ? i3 : xk.w;
        H01.x = h;  H01.y = o1;
        H23.x = o2; H23.y = o3;

        // Gate pre-activations: 4 pk_fma deep per gate (bias preloaded in
        // the lo half of BZ), then one horizontal add. 4-gate ILP.
        f2 t0 = pk_fma(WA01[0], A01, BZ[0]);
        t0 = pk_fma(WA23[0], A23, t0);
        t0 = pk_fma(WB01[0], H01, t0);
        t0 = pk_fma(WB23[0], H23, t0);

        f2 t1 = pk_fma(WA01[1], A01, BZ[1]);
        t1 = pk_fma(WA23[1], A23, t1);
        t1 = pk_fma(WB01[1], H01, t1);
        t1 = pk_fma(WB23[1], H23, t1);

        f2 t2 = pk_fma(WA01[2], A01, BZ[2]);
        t2 = pk_fma(WA23[2], A23, t2);
        t2 = pk_fma(WB01[2], H01, t2);
        t2 = pk_fma(WB23[2], H23, t2);

        f2 t3 = pk_fma(WA01[3], A01, BZ[3]);
        t3 = pk_fma(WA23[3], A23, t3);
        t3 = pk_fma(WB01[3], H01, t3);
        t3 = pk_fma(WB23[3], H23, t3);

        const float z0 = t0.x + t0.y;
        const float z1 = t1.x + t1.y;
        const float z2 = t2.x + t2.y;
        const float z3 = t3.x + t3.y;

        // p_i = e^{-z_i}, p_f = e^{-z_f}, p_g = e^{-2 z_g}, p_o = e^{-z_o}
        const float p0 = fast_exp2(z0);
        const float p1 = fast_exp2(z1);
        const float p2 = fast_exp2(z2);
        const float p3 = fast_exp2(z3);

        // c = sigma(zf)*c + sigma(zi)*tanh(zg), single rcp via common denom:
        //   c = [c*(1+p0)(1+p2) + (1+p1)(1-p2)] / [(1+p0)(1+p1)(1+p2)]
        // rcp(D) is independent of c -> c-recurrence enters via one fmaf.
        const float e0 = 1.0f + p0;
        const float e1 = 1.0f + p1;
        const float e2 = 1.0f + p2;
        const float u2 = e0 * e2;
        const float rD = fast_rcp(u2 * e1);
        const float t2s = e1 * (1.0f - p2);
        const float N  = fmaf(c, u2, t2s);
        c = N * rD;

        // h = sigma(zo) * tanh(c), single rcp:
        //   q = e^{-2|c|};  h = sign(c) * (1-q) / ((1+p3)(1+q))
        const float q   = fast_exp2(NEG2L2E * fabsf(c));
        const float rH  = fast_rcp((1.0f + p3) * (1.0f + q));
        const float mag = (1.0f - q) * rH;
        return copysignf(mag, c);
    };

    // Peel s=0: layer-2 lanes ran on a not-yet-filled pipeline; zero them.
    {
        float hn = do_step(xr[0]);
        xr[0] = xb[(size_t)8 * BB];
        if (isL2) { hn = 0.0f; c = 0.0f; }
        h = hn;
    }

    // Main loop: iteration s computes t=s on layer-1 lanes, t=s-1 on layer-2
    // lanes. Trip count 2048 = 8*256 -> ring index k=s&7 is static per
    // unrolled body; store is guard-free.
#pragma unroll 8
    for (int s = 1; s <= TT; ++s) {
        const int k = s & 7;
        float hn = do_step(xr[k]);
        int tld = s + 8; if (tld > TT - 1) tld = TT - 1;
        xr[k] = xb[(size_t)tld * BB];
        h = hn;
        if (isL2) outp[(size_t)(s - 1) * OUT_STRIDE_T] = hn;
    }
}

extern "C" void kernel_launch(void* const* d_in, const int* in_sizes, int n_in,
                              void* d_out, int out_size, void* d_ws, size_t ws_size,
                              hipStream_t stream)
{
    const float* x    = (const float*)d_in[0];
    const float* wihd = (const float*)d_in[1];
    const float* whhd = (const float*)d_in[2];
    const float* bihd = (const float*)d_in[3];
    const float* bhhd = (const float*)d_in[4];
    const float* wihn = (const float*)d_in[5];
    const float* whhn = (const float*)d_in[6];
    const float* bihn = (const float*)d_in[7];
    const float* bhhn = (const float*)d_in[8];
    float* out = (float*)d_out;

    // 4096 batch elems * 16 lanes = 65536 threads = 256 blocks of 256.
    lstm2x2_kernel<<<dim3(256), dim3(256), 0, stream>>>(
        x, wihd, whhd, bihd, bhhd, wihn, whhn, bihn, bhhn, out);
}